// Round 15
// baseline (76.340 us; speedup 1.0000x reference)
//
#include <hip/hip_runtime.h>

typedef float  f32x4 __attribute__((ext_vector_type(4)));
typedef short  s16x8 __attribute__((ext_vector_type(8)));

// LDS-only barrier (no vmcnt drain): all cross-wave data (red, hbuf, hout) is LDS.
#define LDS_BARRIER() asm volatile("s_waitcnt lgkmcnt(0)\ns_barrier" ::: "memory")

__device__ __forceinline__ unsigned short bfb(float x) {  // f32 -> bf16 bits, RNE
  unsigned u = __builtin_bit_cast(unsigned, x);
  return (unsigned short)((u + 0x7FFFu + ((u >> 16) & 1u)) >> 16);
}
__device__ __forceinline__ float fast_sig(float x) {
  float e = __builtin_amdgcn_exp2f(x * -1.44269504f);
  return __builtin_amdgcn_rcpf(1.f + e);
}
__device__ __forceinline__ float fast_tanh(float x) {
  float e = __builtin_amdgcn_exp2f(x * 2.88539008f);
  return 1.f - 2.f * __builtin_amdgcn_rcpf(1.f + e);
}

// ---------- Phase 1: vocab tables (0..300) + weight A-frags (301..308) + PAIR-sort (309) ----------
__global__ __launch_bounds__(256) void tab_kernel(
    const float* __restrict__ emb,
    const float* __restrict__ Wi, const float* __restrict__ bi,
    const float* __restrict__ Ww, const float* __restrict__ bw,
    const float* __restrict__ Wh, const float* __restrict__ Wu,
    const int* __restrict__ pmask, int* __restrict__ pperm,
    float* __restrict__ xi_tab, float* __restrict__ xw_tab,
    s16x8* __restrict__ frags)
{
  if (blockIdx.x == 309) {   // counting-sort PAIRS by max(len even, len odd), ascending
    __shared__ int hist[33];
    __shared__ int base2[33];
    const int tid = threadIdx.x;
    if (tid < 33) hist[tid] = 0;
    __syncthreads();
    for (int m = tid; m < 4096; m += 256) {
      const int pm = max(pmask[2 * m], pmask[2 * m + 1]);
      atomicAdd(&hist[pm], 1);
    }
    __syncthreads();
    if (tid == 0) {
      int acc = 0;
      for (int l = 1; l <= 32; ++l) { base2[l] = acc; acc += hist[l]; }
    }
    __syncthreads();
    for (int m = tid; m < 4096; m += 256) {
      const int pm = max(pmask[2 * m], pmask[2 * m + 1]);
      const int pos = atomicAdd(&base2[pm], 1);
      pperm[pos] = m;
    }
    return;
  }
  if (blockIdx.x >= 301) {
    const int T = blockIdx.x - 301;      // tile 0..7
    const int lane = threadIdx.x;
    if (lane >= 64) return;
    const int a = lane & 15, s = lane >> 4;
    const float* rowp[3];
    rowp[0] = Wh + (16 * T + a) * 128;          // z tile
    rowp[1] = Wh + (128 + 16 * T + a) * 128;    // r tile
    rowp[2] = Wu + (16 * T + a) * 128;          // hu tile
    #pragma unroll
    for (int mat = 0; mat < 3; ++mat) {
      #pragma unroll
      for (int kk = 0; kk < 4; ++kk) {
        const float* src = rowp[mat] + 32 * kk + 8 * s;
        const float4 A = *(const float4*)src;
        const float4 B = *(const float4*)(src + 4);
        s16x8 v;
        v[0] = (short)bfb(A.x); v[1] = (short)bfb(A.y);
        v[2] = (short)bfb(A.z); v[3] = (short)bfb(A.w);
        v[4] = (short)bfb(B.x); v[5] = (short)bfb(B.y);
        v[6] = (short)bfb(B.z); v[7] = (short)bfb(B.w);
        frags[((mat * 8 + T) * 4 + kk) * 64 + lane] = v;
      }
    }
    return;
  }

  const int v = blockIdx.x;            // 0..300
  const int g = threadIdx.x;           // 0..255
  const float4* er = (const float4*)(emb + v * 128);

  float acc = bi[g];
  const float4* wr = (const float4*)(Wi + g * 128);
  #pragma unroll 8
  for (int j = 0; j < 32; ++j) {
    float4 e = er[j], w4 = wr[j];
    acc = fmaf(e.x, w4.x, acc); acc = fmaf(e.y, w4.y, acc);
    acc = fmaf(e.z, w4.z, acc); acc = fmaf(e.w, w4.w, acc);
  }
  float accw = 0.f;
  if (g < 128) {
    accw = bw[g];
    const float4* wr2 = (const float4*)(Ww + g * 128);
    #pragma unroll 8
    for (int j = 0; j < 32; ++j) {
      float4 e = er[j], w4 = wr2[j];
      accw = fmaf(e.x, w4.x, accw); accw = fmaf(e.y, w4.y, accw);
      accw = fmaf(e.z, w4.z, accw); accw = fmaf(e.w, w4.w, accw);
    }
  }
  __shared__ float rs[4][2], rw[2][2];
  float s = acc, q = acc * acc;
  #pragma unroll
  for (int m = 1; m < 64; m <<= 1) { s += __shfl_xor(s, m); q += __shfl_xor(q, m); }
  if ((threadIdx.x & 63) == 0) { rs[threadIdx.x >> 6][0] = s; rs[threadIdx.x >> 6][1] = q; }
  float sw_ = accw, qw_ = accw * accw;
  #pragma unroll
  for (int m = 1; m < 64; m <<= 1) { sw_ += __shfl_xor(sw_, m); qw_ += __shfl_xor(qw_, m); }
  if (g < 128 && (g & 63) == 0) { rw[g >> 6][0] = sw_; rw[g >> 6][1] = qw_; }
  __syncthreads();
  const float SH = rs[0][0] + rs[1][0] + rs[2][0] + rs[3][0];
  const float QH = rs[0][1] + rs[1][1] + rs[2][1] + rs[3][1];
  const float mH = SH * (1.f / 256.f);
  const float rH = rsqrtf(fmaxf(QH * (1.f / 256.f) - mH * mH, 0.f) + 1e-5f);
  xi_tab[v * 256 + g] = (acc - mH) * rH;
  if (g < 128) {
    const float SW = rw[0][0] + rw[1][0], QW = rw[0][1] + rw[1][1];
    const float mW = SW * (1.f / 128.f);
    const float rW = rsqrtf(fmaxf(QW * (1.f / 128.f) - mW * mW, 0.f) + 1e-5f);
    xw_tab[v * 128 + g] = (accw - mW) * rW;
  }
}

// ---------- Phase 2: recurrence (R14 structure) + block-local fused output LN ----------
// Changes vs R14: (1) dispatch-robust long/short grp interleave, (2) setprio around
// MFMA+stats, (3) shuffle-based stats (4-way fan-in instead of 16).
__global__ __launch_bounds__(256, 2) void rec_kernel(
    const int* __restrict__ paths, const int* __restrict__ pmask,
    const int* __restrict__ pperm,
    const float* __restrict__ bh, const float* __restrict__ bu,
    const float* __restrict__ xi_tab, const float* __restrict__ xw_tab,
    const s16x8* __restrict__ frags,
    const float* __restrict__ gamma, const float* __restrict__ beta,
    float* __restrict__ out)
{
  __shared__ unsigned char hbuf[4096];
  __shared__ alignas(16) float red[4][16][4];   // per-wave {sH,qH,sU,qU} per row
  __shared__ int plT[512];
  __shared__ float hout[16][132];   // parked h per block row (+4 pad)

  const int tid  = threadIdx.x;
  const int w    = tid >> 6;
  const int lane = tid & 63;
  const int s    = lane >> 4;
  const int r    = lane & 15;
  // long/short interleave robust to dispatch order: even blockIdx -> short half,
  // odd blockIdx -> long half. Adjacent blocks (contiguous placement) AND b,b+256
  // (strided placement) both mix long with short on a CU.
  const int grp  = (blockIdx.x & 1) ? (511 - (blockIdx.x >> 1)) : (blockIdx.x >> 1);
  const int pbase = grp * 8;        // 8 pairs per block
  const int gb0  = 32 * w + 4 * s;

  s16x8 wz[2][4], wr2[2][4], wu2[2][4];
  #pragma unroll
  for (int u = 0; u < 2; ++u) {
    const int T = 2 * w + u;
    #pragma unroll
    for (int kk = 0; kk < 4; ++kk) {
      wz[u][kk]  = frags[((0 * 8 + T) * 4 + kk) * 64 + lane];
      wr2[u][kk] = frags[((1 * 8 + T) * 4 + kk) * 64 + lane];
      wu2[u][kk] = frags[((2 * 8 + T) * 4 + kk) * 64 + lane];
    }
  }
  for (int k = tid; k < 512; k += 256) {
    const int j = k & 15;
    const int rid = 2 * pperm[pbase + (j >> 1)] + (j & 1);
    plT[(k >> 4) * 16 + j] = paths[rid * 32 + (k >> 4)];
  }
  ((uint4*)hbuf)[tid] = uint4{0u, 0u, 0u, 0u};

  const int ri  = 2 * pperm[pbase + (r >> 1)] + (r & 1);
  const int len = pmask[ri];
  const int len_max = max(__shfl(len, 14), __shfl(len, 15));  // last pair = block max

  f32x4 bz[2], br2[2], bu2[2];
  #pragma unroll
  for (int u = 0; u < 2; ++u) {
    bz[u]  = *(const f32x4*)(bh + gb0 + 16 * u);
    br2[u] = *(const f32x4*)(bh + 128 + gb0 + 16 * u);
    bu2[u] = *(const f32x4*)(bu + gb0 + 16 * u);
  }
  int hoff[4];
  #pragma unroll
  for (int kk = 0; kk < 4; ++kk)
    hoff[kk] = r * 256 + (((4 * kk + s) ^ r) << 4);
  int hwadr[2];
  #pragma unroll
  for (int u = 0; u < 2; ++u)
    hwadr[u] = r * 256 + (((4 * w + 2 * u + (s >> 1)) ^ r) << 4) + (s & 1) * 8;

  f32x4 hold[2] = {f32x4{0.f,0.f,0.f,0.f}, f32x4{0.f,0.f,0.f,0.f}};

  __syncthreads();   // staging complete

  f32x4 xiz[2], xir[2], xwv[2];
  {
    const int p = plT[r];
    #pragma unroll
    for (int u = 0; u < 2; ++u) {
      xiz[u] = *(const f32x4*)(xi_tab + p * 256 + gb0 + 16 * u);
      xir[u] = *(const f32x4*)(xi_tab + p * 256 + 128 + gb0 + 16 * u);
      xwv[u] = *(const f32x4*)(xw_tab + p * 128 + gb0 + 16 * u);
    }
  }

  #pragma unroll 1
  for (int t = 0; t < len_max; ++t) {
    const int tn = (t + 1 < len_max) ? t + 1 : t;
    const int pn = plT[tn * 16 + r];
    f32x4 nxiz[2], nxir[2], nxwv[2];
    #pragma unroll
    for (int u = 0; u < 2; ++u) {
      nxiz[u] = *(const f32x4*)(xi_tab + pn * 256 + gb0 + 16 * u);
      nxir[u] = *(const f32x4*)(xi_tab + pn * 256 + 128 + gb0 + 16 * u);
      nxwv[u] = *(const f32x4*)(xw_tab + pn * 128 + gb0 + 16 * u);
    }

    // ---- MFMA with bias as accumulator init; setprio favors this wave vs the
    //      co-resident block's waves in their memory/barrier phase (T5 regime) ----
    __builtin_amdgcn_s_setprio(1);
    f32x4 az[2], ar[2], au[2];
    #pragma unroll
    for (int u = 0; u < 2; ++u) { az[u] = bz[u]; ar[u] = br2[u]; au[u] = bu2[u]; }
    #pragma unroll
    for (int kk = 0; kk < 4; ++kk) {
      const s16x8 hb = *(const s16x8*)(hbuf + hoff[kk]);
      #pragma unroll
      for (int u = 0; u < 2; ++u) {
        az[u] = __builtin_amdgcn_mfma_f32_16x16x32_bf16(wz[u][kk],  hb, az[u], 0, 0, 0);
        ar[u] = __builtin_amdgcn_mfma_f32_16x16x32_bf16(wr2[u][kk], hb, ar[u], 0, 0, 0);
        au[u] = __builtin_amdgcn_mfma_f32_16x16x32_bf16(wu2[u][kk], hb, au[u], 0, 0, 0);
      }
    }

    // ---- local stats + 2 shuffles (sum over s-lanes sharing row r) ----
    float sH = 0.f, qH = 0.f, sU = 0.f, qU = 0.f;
    #pragma unroll
    for (int u = 0; u < 2; ++u) {
      #pragma unroll
      for (int i = 0; i < 4; ++i) {
        sH += az[u][i]; qH = fmaf(az[u][i], az[u][i], qH);
        sH += ar[u][i]; qH = fmaf(ar[u][i], ar[u][i], qH);
        sU += au[u][i]; qU = fmaf(au[u][i], au[u][i], qU);
      }
    }
    sH += __shfl_xor(sH, 16); qH += __shfl_xor(qH, 16);
    sU += __shfl_xor(sU, 16); qU += __shfl_xor(qU, 16);
    sH += __shfl_xor(sH, 32); qH += __shfl_xor(qH, 32);
    sU += __shfl_xor(sU, 32); qU += __shfl_xor(qU, 32);
    if (lane < 16) *(f32x4*)&red[w][r][0] = f32x4{sH, qH, sU, qU};
    __builtin_amdgcn_s_setprio(0);

    LDS_BARRIER();   // B1: partials visible; h frag-reads complete

    f32x4 S = *(const f32x4*)&red[0][r][0];
    #pragma unroll
    for (int ww = 1; ww < 4; ++ww) S += *(const f32x4*)&red[ww][r][0];
    const float mH = S[0] * (1.f / 256.f);
    const float rsH = rsqrtf(fmaxf(S[1] * (1.f / 256.f) - mH * mH, 0.f) + 1e-5f);
    const float cH = -mH * rsH;
    const float mU = S[2] * (1.f / 128.f);
    const float rsU = rsqrtf(fmaxf(S[3] * (1.f / 128.f) - mU * mU, 0.f) + 1e-5f);
    const float cU = -mU * rsU;

    f32x4 hn[2];
    #pragma unroll
    for (int u = 0; u < 2; ++u) {
      #pragma unroll
      for (int i = 0; i < 4; ++i) {
        const float zg = fast_sig(xiz[u][i] + fmaf(az[u][i], rsH, cH));
        const float rg = fast_sig(xir[u][i] + fmaf(ar[u][i], rsH, cH));
        const float hu = fmaf(au[u][i], rsU, cU);
        const float hh = fast_tanh(fmaf(rg, hu, xwv[u][i]));
        hn[u][i] = fmaf(zg, hh - hold[u][i], hold[u][i]);
      }
    }
    if (t == len - 1) {   // park final h in LDS (block-local)
      #pragma unroll
      for (int u = 0; u < 2; ++u)
        *(f32x4*)&hout[r][gb0 + 16 * u] = hn[u];
    }
    #pragma unroll
    for (int u = 0; u < 2; ++u) {
      const unsigned lo  = (unsigned)bfb(hn[u][0]) | ((unsigned)bfb(hn[u][1]) << 16);
      const unsigned hi2 = (unsigned)bfb(hn[u][2]) | ((unsigned)bfb(hn[u][3]) << 16);
      *(uint2*)(hbuf + hwadr[u]) = uint2{lo, hi2};
      hold[u] = hn[u];
      xiz[u] = nxiz[u]; xir[u] = nxir[u]; xwv[u] = nxwv[u];
    }
    LDS_BARRIER();   // B2: new h visible for next step
  }

  // ---------- block-local output LN: 8 pairs, wave w handles pairs 2w, 2w+1 ----------
  __syncthreads();   // all parked hout writes visible
  const float g0 = gamma[lane], g1 = gamma[64 + lane], g2 = gamma[128 + lane], g3 = gamma[192 + lane];
  const float b0 = beta[lane],  b1 = beta[64 + lane],  b2 = beta[128 + lane],  b3 = beta[192 + lane];
  #pragma unroll
  for (int e = 0; e < 2; ++e) {
    const int q = 2 * w + e;                 // local pair 0..7
    const int pair = pperm[pbase + q];       // global pair id
    const float oa0 = hout[2 * q][lane],     oa1 = hout[2 * q][64 + lane];
    const float ob0 = hout[2 * q + 1][lane], ob1 = hout[2 * q + 1][64 + lane];
    float ss = oa0 + oa1 + ob0 + ob1;
    float qq = oa0 * oa0 + oa1 * oa1 + ob0 * ob0 + ob1 * ob1;
    #pragma unroll
    for (int msk = 1; msk < 64; msk <<= 1) { ss += __shfl_xor(ss, msk); qq += __shfl_xor(qq, msk); }
    const float mean = ss * (1.f / 256.f);
    const float rstd = rsqrtf(fmaxf(qq * (1.f / 256.f) - mean * mean, 0.f) + 1e-5f);
    const float na0 = (oa0 - mean) * rstd, na1 = (oa1 - mean) * rstd;
    const float nb0 = (ob0 - mean) * rstd, nb1 = (ob1 - mean) * rstd;
    float* pa = out + (size_t)(2 * pair) * 256;
    float* pb = pa + 256;
    pa[lane]       = na0 * g0 + b0;
    pa[64 + lane]  = na1 * g1 + b1;
    pa[128 + lane] = nb0 * g2 + b2;
    pa[192 + lane] = nb1 * g3 + b3;
    pb[lane]       = nb0 * g0 + b0;
    pb[64 + lane]  = nb1 * g1 + b1;
    pb[128 + lane] = na0 * g2 + b2;
    pb[192 + lane] = na1 * g3 + b3;
  }
}

extern "C" void kernel_launch(void* const* d_in, const int* in_sizes, int n_in,
                              void* d_out, int out_size, void* d_ws, size_t ws_size,
                              hipStream_t stream) {
  const int*   paths = (const int*)d_in[0];
  const int*   pmask = (const int*)d_in[1];
  const float* emb   = (const float*)d_in[2];
  const float* Wi    = (const float*)d_in[3];
  const float* bi    = (const float*)d_in[4];
  const float* Wh    = (const float*)d_in[5];
  const float* bh    = (const float*)d_in[6];
  const float* Ww    = (const float*)d_in[7];
  const float* bw    = (const float*)d_in[8];
  const float* Wu    = (const float*)d_in[9];
  const float* bu    = (const float*)d_in[10];
  const float* gamma = (const float*)d_in[11];
  const float* beta  = (const float*)d_in[12];
  float* out = (float*)d_out;

  float* xi_tab = (float*)d_ws;                          // [301][256] f32
  float* xw_tab = xi_tab + 301 * 256;                    // [301][128] f32
  s16x8* frags  = (s16x8*)((char*)d_ws + 462336);        // [3*8*4][64] s16x8 = 96 KB
  int*   pperm  = (int*)((char*)d_ws + 560640);          // [4096] pair permutation

  hipLaunchKernelGGL(tab_kernel, dim3(310), dim3(256), 0, stream,
                     emb, Wi, bi, Ww, bw, Wh, Wu, pmask, pperm, xi_tab, xw_tab, frags);
  hipLaunchKernelGGL(rec_kernel, dim3(512), dim3(256), 0, stream,
                     paths, pmask, pperm, bh, bu, xi_tab, xw_tab, frags,
                     gamma, beta, out);
}

// Round 16
// 74.061 us; speedup vs baseline: 1.0308x; 1.0308x over previous
//
#include <hip/hip_runtime.h>

typedef float  f32x4 __attribute__((ext_vector_type(4)));
typedef short  s16x8 __attribute__((ext_vector_type(8)));

// LDS-only barrier (no vmcnt drain): all cross-wave data (red, hbuf, hout) is LDS.
#define LDS_BARRIER() asm volatile("s_waitcnt lgkmcnt(0)\ns_barrier" ::: "memory")

__device__ __forceinline__ unsigned short bfb(float x) {  // f32 -> bf16 bits, RNE
  unsigned u = __builtin_bit_cast(unsigned, x);
  return (unsigned short)((u + 0x7FFFu + ((u >> 16) & 1u)) >> 16);
}
__device__ __forceinline__ float fast_sig(float x) {
  float e = __builtin_amdgcn_exp2f(x * -1.44269504f);
  return __builtin_amdgcn_rcpf(1.f + e);
}
__device__ __forceinline__ float fast_tanh(float x) {
  float e = __builtin_amdgcn_exp2f(x * 2.88539008f);
  return 1.f - 2.f * __builtin_amdgcn_rcpf(1.f + e);
}

// ---------- Phase 1: vocab tables (0..300) + weight A-frags (301..308) + PAIR-sort (309) ----------
__global__ __launch_bounds__(256) void tab_kernel(
    const float* __restrict__ emb,
    const float* __restrict__ Wi, const float* __restrict__ bi,
    const float* __restrict__ Ww, const float* __restrict__ bw,
    const float* __restrict__ Wh, const float* __restrict__ Wu,
    const int* __restrict__ pmask, int* __restrict__ pperm,
    float* __restrict__ xi_tab, float* __restrict__ xw_tab,
    s16x8* __restrict__ frags)
{
  if (blockIdx.x == 309) {   // counting-sort PAIRS by max(len even, len odd), ascending
    __shared__ int hist[33];
    __shared__ int base2[33];
    const int tid = threadIdx.x;
    if (tid < 33) hist[tid] = 0;
    __syncthreads();
    for (int m = tid; m < 4096; m += 256) {
      const int pm = max(pmask[2 * m], pmask[2 * m + 1]);
      atomicAdd(&hist[pm], 1);
    }
    __syncthreads();
    if (tid == 0) {
      int acc = 0;
      for (int l = 1; l <= 32; ++l) { base2[l] = acc; acc += hist[l]; }
    }
    __syncthreads();
    for (int m = tid; m < 4096; m += 256) {
      const int pm = max(pmask[2 * m], pmask[2 * m + 1]);
      const int pos = atomicAdd(&base2[pm], 1);
      pperm[pos] = m;
    }
    return;
  }
  if (blockIdx.x >= 301) {
    const int T = blockIdx.x - 301;      // tile 0..7
    const int lane = threadIdx.x;
    if (lane >= 64) return;
    const int a = lane & 15, s = lane >> 4;
    const float* rowp[3];
    rowp[0] = Wh + (16 * T + a) * 128;          // z tile
    rowp[1] = Wh + (128 + 16 * T + a) * 128;    // r tile
    rowp[2] = Wu + (16 * T + a) * 128;          // hu tile
    #pragma unroll
    for (int mat = 0; mat < 3; ++mat) {
      #pragma unroll
      for (int kk = 0; kk < 4; ++kk) {
        const float* src = rowp[mat] + 32 * kk + 8 * s;
        const float4 A = *(const float4*)src;
        const float4 B = *(const float4*)(src + 4);
        s16x8 v;
        v[0] = (short)bfb(A.x); v[1] = (short)bfb(A.y);
        v[2] = (short)bfb(A.z); v[3] = (short)bfb(A.w);
        v[4] = (short)bfb(B.x); v[5] = (short)bfb(B.y);
        v[6] = (short)bfb(B.z); v[7] = (short)bfb(B.w);
        frags[((mat * 8 + T) * 4 + kk) * 64 + lane] = v;
      }
    }
    return;
  }

  const int v = blockIdx.x;            // 0..300
  const int g = threadIdx.x;           // 0..255
  const float4* er = (const float4*)(emb + v * 128);

  float acc = bi[g];
  const float4* wr = (const float4*)(Wi + g * 128);
  #pragma unroll 8
  for (int j = 0; j < 32; ++j) {
    float4 e = er[j], w4 = wr[j];
    acc = fmaf(e.x, w4.x, acc); acc = fmaf(e.y, w4.y, acc);
    acc = fmaf(e.z, w4.z, acc); acc = fmaf(e.w, w4.w, acc);
  }
  float accw = 0.f;
  if (g < 128) {
    accw = bw[g];
    const float4* wr2 = (const float4*)(Ww + g * 128);
    #pragma unroll 8
    for (int j = 0; j < 32; ++j) {
      float4 e = er[j], w4 = wr2[j];
      accw = fmaf(e.x, w4.x, accw); accw = fmaf(e.y, w4.y, accw);
      accw = fmaf(e.z, w4.z, accw); accw = fmaf(e.w, w4.w, accw);
    }
  }
  __shared__ float rs[4][2], rw[2][2];
  float s = acc, q = acc * acc;
  #pragma unroll
  for (int m = 1; m < 64; m <<= 1) { s += __shfl_xor(s, m); q += __shfl_xor(q, m); }
  if ((threadIdx.x & 63) == 0) { rs[threadIdx.x >> 6][0] = s; rs[threadIdx.x >> 6][1] = q; }
  float sw_ = accw, qw_ = accw * accw;
  #pragma unroll
  for (int m = 1; m < 64; m <<= 1) { sw_ += __shfl_xor(sw_, m); qw_ += __shfl_xor(qw_, m); }
  if (g < 128 && (g & 63) == 0) { rw[g >> 6][0] = sw_; rw[g >> 6][1] = qw_; }
  __syncthreads();
  const float SH = rs[0][0] + rs[1][0] + rs[2][0] + rs[3][0];
  const float QH = rs[0][1] + rs[1][1] + rs[2][1] + rs[3][1];
  const float mH = SH * (1.f / 256.f);
  const float rH = rsqrtf(fmaxf(QH * (1.f / 256.f) - mH * mH, 0.f) + 1e-5f);
  xi_tab[v * 256 + g] = (acc - mH) * rH;
  if (g < 128) {
    const float SW = rw[0][0] + rw[1][0], QW = rw[0][1] + rw[1][1];
    const float mW = SW * (1.f / 128.f);
    const float rW = rsqrtf(fmaxf(QW * (1.f / 128.f) - mW * mW, 0.f) + 1e-5f);
    xw_tab[v * 128 + g] = (accw - mW) * rW;
  }
}

// ---------- Phase 2: recurrence (R10 structure) + block-local fused output LN ----------
// Block owns 8 COMPLETE pairs (16 rows); parked h -> LDS; final pair-LN in-block.
__global__ __launch_bounds__(256, 2) void rec_kernel(
    const int* __restrict__ paths, const int* __restrict__ pmask,
    const int* __restrict__ pperm,
    const float* __restrict__ bh, const float* __restrict__ bu,
    const float* __restrict__ xi_tab, const float* __restrict__ xw_tab,
    const s16x8* __restrict__ frags,
    const float* __restrict__ gamma, const float* __restrict__ beta,
    float* __restrict__ out)
{
  __shared__ unsigned char hbuf[4096];
  __shared__ alignas(16) float red[4][4][16][4];
  __shared__ int plT[512];
  __shared__ float hout[16][132];   // parked h per block row (+4 pad)

  const int tid  = threadIdx.x;
  const int w    = tid >> 6;
  const int lane = tid & 63;
  const int s    = lane >> 4;
  const int r    = lane & 15;
  const int grp  = (blockIdx.x < 256) ? blockIdx.x : 767 - blockIdx.x;  // snake
  const int pbase = grp * 8;        // 8 pairs per block
  const int gb0  = 32 * w + 4 * s;

  s16x8 wz[2][4], wr2[2][4], wu2[2][4];
  #pragma unroll
  for (int u = 0; u < 2; ++u) {
    const int T = 2 * w + u;
    #pragma unroll
    for (int kk = 0; kk < 4; ++kk) {
      wz[u][kk]  = frags[((0 * 8 + T) * 4 + kk) * 64 + lane];
      wr2[u][kk] = frags[((1 * 8 + T) * 4 + kk) * 64 + lane];
      wu2[u][kk] = frags[((2 * 8 + T) * 4 + kk) * 64 + lane];
    }
  }
  for (int k = tid; k < 512; k += 256) {
    const int j = k & 15;
    const int rid = 2 * pperm[pbase + (j >> 1)] + (j & 1);
    plT[(k >> 4) * 16 + j] = paths[rid * 32 + (k >> 4)];
  }
  ((uint4*)hbuf)[tid] = uint4{0u, 0u, 0u, 0u};

  const int ri  = 2 * pperm[pbase + (r >> 1)] + (r & 1);
  const int len = pmask[ri];
  const int len_max = max(__shfl(len, 14), __shfl(len, 15));  // last pair holds block max

  f32x4 bz[2], br2[2], bu2[2];
  #pragma unroll
  for (int u = 0; u < 2; ++u) {
    bz[u]  = *(const f32x4*)(bh + gb0 + 16 * u);
    br2[u] = *(const f32x4*)(bh + 128 + gb0 + 16 * u);
    bu2[u] = *(const f32x4*)(bu + gb0 + 16 * u);
  }
  int hoff[4];
  #pragma unroll
  for (int kk = 0; kk < 4; ++kk)
    hoff[kk] = r * 256 + (((4 * kk + s) ^ r) << 4);
  int hwadr[2];
  #pragma unroll
  for (int u = 0; u < 2; ++u)
    hwadr[u] = r * 256 + (((4 * w + 2 * u + (s >> 1)) ^ r) << 4) + (s & 1) * 8;

  f32x4 hold[2] = {f32x4{0.f,0.f,0.f,0.f}, f32x4{0.f,0.f,0.f,0.f}};

  __syncthreads();   // staging complete

  f32x4 xiz[2], xir[2], xwv[2];
  {
    const int p = plT[r];
    #pragma unroll
    for (int u = 0; u < 2; ++u) {
      xiz[u] = *(const f32x4*)(xi_tab + p * 256 + gb0 + 16 * u);
      xir[u] = *(const f32x4*)(xi_tab + p * 256 + 128 + gb0 + 16 * u);
      xwv[u] = *(const f32x4*)(xw_tab + p * 128 + gb0 + 16 * u);
    }
  }

  #pragma unroll 1
  for (int t = 0; t < len_max; ++t) {
    const int tn = (t + 1 < len_max) ? t + 1 : t;
    const int pn = plT[tn * 16 + r];
    f32x4 nxiz[2], nxir[2], nxwv[2];
    #pragma unroll
    for (int u = 0; u < 2; ++u) {
      nxiz[u] = *(const f32x4*)(xi_tab + pn * 256 + gb0 + 16 * u);
      nxir[u] = *(const f32x4*)(xi_tab + pn * 256 + 128 + gb0 + 16 * u);
      nxwv[u] = *(const f32x4*)(xw_tab + pn * 128 + gb0 + 16 * u);
    }

    // MFMA with bias as accumulator init
    f32x4 az[2], ar[2], au[2];
    #pragma unroll
    for (int u = 0; u < 2; ++u) { az[u] = bz[u]; ar[u] = br2[u]; au[u] = bu2[u]; }
    #pragma unroll
    for (int kk = 0; kk < 4; ++kk) {
      const s16x8 hb = *(const s16x8*)(hbuf + hoff[kk]);
      #pragma unroll
      for (int u = 0; u < 2; ++u) {
        az[u] = __builtin_amdgcn_mfma_f32_16x16x32_bf16(wz[u][kk],  hb, az[u], 0, 0, 0);
        ar[u] = __builtin_amdgcn_mfma_f32_16x16x32_bf16(wr2[u][kk], hb, ar[u], 0, 0, 0);
        au[u] = __builtin_amdgcn_mfma_f32_16x16x32_bf16(wu2[u][kk], hb, au[u], 0, 0, 0);
      }
    }

    float sH = 0.f, qH = 0.f, sU = 0.f, qU = 0.f;
    #pragma unroll
    for (int u = 0; u < 2; ++u) {
      #pragma unroll
      for (int i = 0; i < 4; ++i) {
        sH += az[u][i]; qH = fmaf(az[u][i], az[u][i], qH);
        sH += ar[u][i]; qH = fmaf(ar[u][i], ar[u][i], qH);
        sU += au[u][i]; qU = fmaf(au[u][i], au[u][i], qU);
      }
    }
    *(f32x4*)&red[w][s][r][0] = f32x4{sH, qH, sU, qU};

    LDS_BARRIER();   // B1

    f32x4 acc0 = *(const f32x4*)&red[0][0][r][0];
    f32x4 acc1 = *(const f32x4*)&red[0][1][r][0];
    #pragma unroll
    for (int c = 2; c < 16; c += 2) {
      acc0 += *(const f32x4*)&red[c >> 2][c & 3][r][0];
      acc1 += *(const f32x4*)&red[(c + 1) >> 2][(c + 1) & 3][r][0];
    }
    const f32x4 S = acc0 + acc1;
    const float mH = S[0] * (1.f / 256.f);
    const float rsH = rsqrtf(fmaxf(S[1] * (1.f / 256.f) - mH * mH, 0.f) + 1e-5f);
    const float cH = -mH * rsH;
    const float mU = S[2] * (1.f / 128.f);
    const float rsU = rsqrtf(fmaxf(S[3] * (1.f / 128.f) - mU * mU, 0.f) + 1e-5f);
    const float cU = -mU * rsU;

    f32x4 hn[2];
    #pragma unroll
    for (int u = 0; u < 2; ++u) {
      #pragma unroll
      for (int i = 0; i < 4; ++i) {
        const float zg = fast_sig(xiz[u][i] + fmaf(az[u][i], rsH, cH));
        const float rg = fast_sig(xir[u][i] + fmaf(ar[u][i], rsH, cH));
        const float hu = fmaf(au[u][i], rsU, cU);
        const float hh = fast_tanh(fmaf(rg, hu, xwv[u][i]));
        hn[u][i] = fmaf(zg, hh - hold[u][i], hold[u][i]);
      }
    }
    if (t == len - 1) {   // park final h in LDS (block-local)
      #pragma unroll
      for (int u = 0; u < 2; ++u)
        *(f32x4*)&hout[r][gb0 + 16 * u] = hn[u];
    }
    #pragma unroll
    for (int u = 0; u < 2; ++u) {
      const unsigned lo  = (unsigned)bfb(hn[u][0]) | ((unsigned)bfb(hn[u][1]) << 16);
      const unsigned hi2 = (unsigned)bfb(hn[u][2]) | ((unsigned)bfb(hn[u][3]) << 16);
      *(uint2*)(hbuf + hwadr[u]) = uint2{lo, hi2};
      hold[u] = hn[u];
      xiz[u] = nxiz[u]; xir[u] = nxir[u]; xwv[u] = nxwv[u];
    }
    LDS_BARRIER();   // B2
  }

  // ---------- block-local output LN: 8 pairs, wave w handles pairs 2w, 2w+1 ----------
  __syncthreads();   // all parked hout writes visible
  const float g0 = gamma[lane], g1 = gamma[64 + lane], g2 = gamma[128 + lane], g3 = gamma[192 + lane];
  const float b0 = beta[lane],  b1 = beta[64 + lane],  b2 = beta[128 + lane],  b3 = beta[192 + lane];
  #pragma unroll
  for (int e = 0; e < 2; ++e) {
    const int q = 2 * w + e;                 // local pair 0..7
    const int pair = pperm[pbase + q];       // global pair id
    const float oa0 = hout[2 * q][lane],     oa1 = hout[2 * q][64 + lane];
    const float ob0 = hout[2 * q + 1][lane], ob1 = hout[2 * q + 1][64 + lane];
    float ss = oa0 + oa1 + ob0 + ob1;
    float qq = oa0 * oa0 + oa1 * oa1 + ob0 * ob0 + ob1 * ob1;
    #pragma unroll
    for (int msk = 1; msk < 64; msk <<= 1) { ss += __shfl_xor(ss, msk); qq += __shfl_xor(qq, msk); }
    const float mean = ss * (1.f / 256.f);
    const float rstd = rsqrtf(fmaxf(qq * (1.f / 256.f) - mean * mean, 0.f) + 1e-5f);
    const float na0 = (oa0 - mean) * rstd, na1 = (oa1 - mean) * rstd;
    const float nb0 = (ob0 - mean) * rstd, nb1 = (ob1 - mean) * rstd;
    float* pa = out + (size_t)(2 * pair) * 256;
    float* pb = pa + 256;
    pa[lane]       = na0 * g0 + b0;
    pa[64 + lane]  = na1 * g1 + b1;
    pa[128 + lane] = nb0 * g2 + b2;
    pa[192 + lane] = nb1 * g3 + b3;
    pb[lane]       = nb0 * g0 + b0;
    pb[64 + lane]  = nb1 * g1 + b1;
    pb[128 + lane] = na0 * g2 + b2;
    pb[192 + lane] = na1 * g3 + b3;
  }
}

extern "C" void kernel_launch(void* const* d_in, const int* in_sizes, int n_in,
                              void* d_out, int out_size, void* d_ws, size_t ws_size,
                              hipStream_t stream) {
  const int*   paths = (const int*)d_in[0];
  const int*   pmask = (const int*)d_in[1];
  const float* emb   = (const float*)d_in[2];
  const float* Wi    = (const float*)d_in[3];
  const float* bi    = (const float*)d_in[4];
  const float* Wh    = (const float*)d_in[5];
  const float* bh    = (const float*)d_in[6];
  const float* Ww    = (const float*)d_in[7];
  const float* bw    = (const float*)d_in[8];
  const float* Wu    = (const float*)d_in[9];
  const float* bu    = (const float*)d_in[10];
  const float* gamma = (const float*)d_in[11];
  const float* beta  = (const float*)d_in[12];
  float* out = (float*)d_out;

  float* xi_tab = (float*)d_ws;                          // [301][256] f32
  float* xw_tab = xi_tab + 301 * 256;                    // [301][128] f32
  s16x8* frags  = (s16x8*)((char*)d_ws + 462336);        // [3*8*4][64] s16x8 = 96 KB
  int*   pperm  = (int*)((char*)d_ws + 560640);          // [4096] pair permutation

  hipLaunchKernelGGL(tab_kernel, dim3(310), dim3(256), 0, stream,
                     emb, Wi, bi, Ww, bw, Wh, Wu, pmask, pperm, xi_tab, xw_tab, frags);
  hipLaunchKernelGGL(rec_kernel, dim3(512), dim3(256), 0, stream,
                     paths, pmask, pperm, bh, bu, xi_tab, xw_tab, frags,
                     gamma, beta, out);
}